// Round 1
// baseline (271.401 us; speedup 1.0000x reference)
//
#include <hip/hip_runtime.h>
#include <math.h>

// Chamfer distance, B=8, N=M=8192, D=3, fp32.
// out = mean_m( min_n dist2(x_n, y_m) ) + mean_n( min_m dist2(x_n, y_m) )
//
// Strategy: dist2 = |x|^2 + |t|^2 - 2 x.t  (same expansion as the reference).
// Precompute target quads (-2t0, -2t1, -2t2, |t|^2); a pair then costs
// mul + fma + fma + add + min on the vector pipe while the quad streams
// through the SCALAR pipe (wave-uniform loop index -> s_load_dwordx4).

#define B_  8
#define N_  8192
#define M_  8192

// ws layout (4-byte units):
//   [0,            BN)      : minX  (uint bits of per-x min dist2)
//   [BN,           BN+BM)   : minY
//   [BN+BM, ...)            : quadX float4[BN], then quadY float4[BM]

__global__ void prep_kernel(const float* __restrict__ x, const float* __restrict__ y,
                            unsigned* __restrict__ umin,
                            float4* __restrict__ quadX, float4* __restrict__ quadY,
                            int BN, int BM) {
    int i = blockIdx.x * blockDim.x + threadIdx.x;
    if (i >= BN + BM) return;
    umin[i] = 0x7F800000u;  // +inf bits
    const float* src;
    float4* dst;
    int k;
    if (i < BN) { src = x; dst = quadX; k = i; }
    else        { src = y; dst = quadY; k = i - BN; }
    float a0 = src[3 * k + 0];
    float a1 = src[3 * k + 1];
    float a2 = src[3 * k + 2];
    dst[k] = make_float4(-2.0f * a0, -2.0f * a1, -2.0f * a2,
                         fmaf(a0, a0, fmaf(a1, a1, a2 * a2)));
}

// One query point per thread; blockIdx.z selects a chunk of targets.
// q: raw query points [B, NQ, 3]; tq: target quads [B, NT]; omin: [B, NQ].
__global__ __launch_bounds__(256)
void minpass_kernel(const float* __restrict__ q, const float4* __restrict__ tq,
                    unsigned* __restrict__ omin, int NT, int CHUNK) {
    const int b  = blockIdx.y;
    const int iq = blockIdx.x * blockDim.x + threadIdx.x;
    const int NQ = gridDim.x * blockDim.x;

    const float* qp = q + ((long)b * NQ + iq) * 3;
    const float x0 = qp[0], x1 = qp[1], x2 = qp[2];
    const float xn = fmaf(x0, x0, fmaf(x1, x1, x2 * x2));

    // Wave-uniform base + uniform loop index -> scalar loads of the quads.
    const float4* base = tq + (long)b * NT + (long)blockIdx.z * CHUNK;

    float m = __builtin_inff();
    for (int j = 0; j < CHUNK; j += 4) {
        float4 t0 = base[j + 0];
        float4 t1 = base[j + 1];
        float4 t2 = base[j + 2];
        float4 t3 = base[j + 3];
        // score = x . (-2t) + |t|^2   (each VALU op uses <=1 SGPR operand)
        float s0 = fmaf(x0, t0.x, fmaf(x1, t0.y, x2 * t0.z)) + t0.w;
        float s1 = fmaf(x0, t1.x, fmaf(x1, t1.y, x2 * t1.z)) + t1.w;
        float s2 = fmaf(x0, t2.x, fmaf(x1, t2.y, x2 * t2.z)) + t2.w;
        float s3 = fmaf(x0, t3.x, fmaf(x1, t3.y, x2 * t3.z)) + t3.w;
        m = fminf(fminf(m, fminf(s0, s1)), fminf(s2, s3));   // hopes for v_min3
    }
    // min dist2 for this chunk; clamp tiny negative cancellation so that
    // uint-ordered atomicMin is exact (dist2 >= 0).
    float d = fmaxf(m + xn, 0.0f);
    atomicMin(omin + (long)b * NQ + iq, __float_as_uint(d));
}

// Single-block deterministic reduction: out = (sum of all mins) / 65536.
__global__ __launch_bounds__(1024)
void reduce_kernel(const unsigned* __restrict__ umin, float* __restrict__ out,
                   int total, float scale) {
    float s = 0.0f;
    for (int i = threadIdx.x; i < total; i += blockDim.x)
        s += __uint_as_float(umin[i]);
    for (int off = 32; off > 0; off >>= 1)
        s += __shfl_down(s, off, 64);
    __shared__ float wsum[16];
    const int lane = threadIdx.x & 63;
    const int w    = threadIdx.x >> 6;
    if (lane == 0) wsum[w] = s;
    __syncthreads();
    if (threadIdx.x == 0) {
        float t = 0.0f;
        const int nw = blockDim.x >> 6;
        for (int i = 0; i < nw; ++i) t += wsum[i];
        out[0] = t * scale;
    }
}

extern "C" void kernel_launch(void* const* d_in, const int* in_sizes, int n_in,
                              void* d_out, int out_size, void* d_ws, size_t ws_size,
                              hipStream_t stream) {
    const float* x = (const float*)d_in[0];  // [8, 8192, 3]
    const float* y = (const float*)d_in[1];  // [8, 8192, 3]
    float* out = (float*)d_out;

    const int BN = B_ * N_;
    const int BM = B_ * M_;

    unsigned* umin  = (unsigned*)d_ws;
    float4*   quadX = (float4*)((char*)d_ws + (size_t)(BN + BM) * 4);
    float4*   quadY = quadX + BN;

    prep_kernel<<<(BN + BM + 255) / 256, 256, 0, stream>>>(x, y, umin, quadX, quadY, BN, BM);

    const int S = 8;  // target-dimension splits -> 32*8*8 = 2048 blocks / pass
    // per-x mins: queries = x, targets = y quads
    minpass_kernel<<<dim3(N_ / 256, B_, S), 256, 0, stream>>>(x, quadY, umin, M_, M_ / S);
    // per-y mins: queries = y, targets = x quads
    minpass_kernel<<<dim3(M_ / 256, B_, S), 256, 0, stream>>>(y, quadX, umin + BN, N_, N_ / S);

    reduce_kernel<<<1, 1024, 0, stream>>>(umin, out, BN + BM, 1.0f / 65536.0f);
}